// Round 5
// baseline (11286.549 us; speedup 1.0000x reference)
//
#include <hip/hip_runtime.h>
#include <cstddef>
#include <cstring>

// Shapes (fixed by the reference)
#define BB 4
#define SS 512
#define VV 32000
#define EE 512
#define HH 1024
#define DM 256
#define UU 4096
#define MM 1024
#define TT 1536   // MM + SS

// ---------------- device helpers ----------------
__device__ __forceinline__ float sigmoidf_(float x) { return 1.f / (1.f + __expf(-x)); }

// ---------------- generic fp32 GEMM:  C[M,N] = act( A[M,K] @ W[N,K]^T + bias ) ----------------
template <int TILE, int MICRO>
__global__ __launch_bounds__(256) void gemm_k(
    const float* __restrict__ A, const int* __restrict__ a_idx,
    const float* __restrict__ W, const float* __restrict__ bias,
    float* __restrict__ C, int K, int ldc, int act, const int* __restrict__ sidx)
{
  constexpr int PITCH = TILE + 4;           // 132 / 68: row bytes stay 16B-aligned
  __shared__ float As[16][PITCH];
  __shared__ float Ws[16][PITCH];
  const int tid = threadIdx.x;
  const int bm = blockIdx.y * TILE, bn = blockIdx.x * TILE;
  const int tr = tid >> 4, tc = tid & 15;
  const int lk = tid & 15, lr0 = tid >> 4;
  float acc[MICRO][MICRO] = {};

  for (int k0 = 0; k0 < K; k0 += 16) {
#pragma unroll
    for (int jj = 0; jj < TILE / 16; ++jj) {
      int row = lr0 + (jj << 4);
      int am = bm + row;
      int ar = a_idx ? a_idx[am] : am;
      As[lk][row] = A[(size_t)ar * K + k0 + lk];
      Ws[lk][row] = W[(size_t)(bn + row) * K + k0 + lk];
    }
    __syncthreads();
#pragma unroll
    for (int kk = 0; kk < 16; ++kk) {
      float av[MICRO], wv[MICRO];
#pragma unroll
      for (int i = 0; i < MICRO; ++i) av[i] = As[kk][tr * MICRO + i];
#pragma unroll
      for (int j = 0; j < MICRO; ++j) wv[j] = Ws[kk][tc * MICRO + j];
#pragma unroll
      for (int i = 0; i < MICRO; ++i)
#pragma unroll
        for (int j = 0; j < MICRO; ++j) acc[i][j] += av[i] * wv[j];
    }
    __syncthreads();
  }

#pragma unroll
  for (int i = 0; i < MICRO; ++i) {
    int m = bm + tr * MICRO + i;
    float tmp[MICRO];
#pragma unroll
    for (int j = 0; j < MICRO; ++j) {
      int n = bn + tc * MICRO + j;
      float v = acc[i][j] + bias[n];
      if (act == 1) { v = fmaxf(v, 0.f); v *= v; }   // square(relu(x))
      tmp[j] = v;
    }
    if (sidx) {
#pragma unroll
      for (int j = 0; j < MICRO; ++j)
        atomicAdd(C + (size_t)m * ldc + sidx[bn + tc * MICRO + j], tmp[j]);
    } else {
      float* cp = C + (size_t)m * ldc + bn + tc * MICRO;
#pragma unroll
      for (int j4 = 0; j4 < MICRO / 4; ++j4)
        *(float4*)(cp + 4 * j4) =
            make_float4(tmp[4 * j4], tmp[4 * j4 + 1], tmp[4 * j4 + 2], tmp[4 * j4 + 3]);
    }
  }
}

// ---------------- GRU scan: persistent grid, one wave per h-column ----------------
// 64 WGs x 1024 threads = 1024 waves = 1024 columns. Recurrent weights in registers.
// Per step:
//   compute from LDS h -> lane0s drop hv4 into LDS scratch (+plain states stores, L2-ack)
//   -> barrier1
//   -> wave0: publish 64 values (coalesced 4B agent atomic stores, write-through to MALL),
//      s_waitcnt vmcnt(0) (whole wave's stores at coherence point), relaxed flag store
//   -> every wave: poll 64 padded flags (1 load/lane)
//      -> agent-acquire fence (buffer_inv: drops stale L1/L2 lines)
//      -> PLAIN float4 gather (1024x16B coalesced, cached) -> LDS -> barrier2.
// Safety (2-buffer, distance-2): publishing t+3 (overwriting buf[(t+1)&1]) requires
// observing all flags >= t+2, which requires every WG to have completed its t+1 gather
// (gather loads complete before compute before publish, and barriers order waves).
__global__ __launch_bounds__(1024, 1) void gru_scan(
    const float* __restrict__ xp,    // [B*S][3H]  (x@w_ih^T + b_ih)
    const float* __restrict__ w_hh,  // [3H][H]
    const float* __restrict__ b_hh,  // [3H]
    float* __restrict__ states,      // [B*S][H]
    float* hdata,                    // [2][H][4] floats (32 KB)
    unsigned* flags)                 // [64*16] per-WG epoch flags, 64B stride, zeroed
{
  __shared__ float h_lds[4 * HH];    // 16 KB: [bb][col]
  __shared__ float pub[16][4];       // lane0 scratch: [wave][bb]
  const int tid = threadIdx.x;
  const int lane = tid & 63;
  const int wv = tid >> 6;
  const int j = (blockIdx.x << 4) + wv;   // h column owned by this wave

  float wreg[3][16];
#pragma unroll
  for (int g = 0; g < 3; ++g) {
    const float* wr = w_hh + (size_t)((g << 10) + j) * HH + lane;
#pragma unroll
    for (int i = 0; i < 16; ++i) wreg[g][i] = wr[i << 6];
  }
  const float bh0 = b_hh[j], bh1 = b_hh[HH + j], bh2 = b_hh[2 * HH + j];

  // h0 = 0
  for (int i = tid; i < 4 * HH; i += 1024) h_lds[i] = 0.f;
  __syncthreads();

  for (int t = 0; t < SS; ++t) {
    // xp loads first so their latency hides under LDS reads + FMAs
    float xr[4], xz[4], xn[4];
#pragma unroll
    for (int bb = 0; bb < 4; ++bb) {
      const float* xpr = xp + (size_t)((bb << 9) + t) * 3072 + j;
      xr[bb] = xpr[0]; xz[bb] = xpr[HH]; xn[bb] = xpr[2 * HH];
    }

    float acc[4][3] = {};
    float hold[4];
#pragma unroll
    for (int bb = 0; bb < 4; ++bb) {
      hold[bb] = h_lds[(bb << 10) + j];
#pragma unroll
      for (int i = 0; i < 16; ++i) {
        float hv = h_lds[(bb << 10) + (i << 6) + lane];
        acc[bb][0] += hv * wreg[0][i];
        acc[bb][1] += hv * wreg[1][i];
        acc[bb][2] += hv * wreg[2][i];
      }
    }
#pragma unroll
    for (int off = 32; off >= 1; off >>= 1)
#pragma unroll
      for (int bb = 0; bb < 4; ++bb) {
        acc[bb][0] += __shfl_xor(acc[bb][0], off, 64);
        acc[bb][1] += __shfl_xor(acc[bb][1], off, 64);
        acc[bb][2] += __shfl_xor(acc[bb][2], off, 64);
      }
    if (lane == 0) {
#pragma unroll
      for (int bb = 0; bb < 4; ++bb) {
        float r = sigmoidf_(xr[bb] + acc[bb][0] + bh0);
        float z = sigmoidf_(xz[bb] + acc[bb][1] + bh1);
        float n = tanhf(xn[bb] + r * (acc[bb][2] + bh2));
        float hv = (1.f - z) * n + z * hold[bb];
        pub[wv][bb] = hv;
        states[(size_t)((bb << 9) + t) * HH + j] = hv;   // plain store, L2-ack
      }
    }
    if (t == SS - 1) break;            // last state written; no more exchange needed

    __syncthreads();                   // barrier1: pub ready, all h_lds reads done

    const int parity = (t + 1) & 1;
    if (wv == 0) {
      // publish: 64 lanes, one float each -> coalesced 256B of agent-scope stores
      float v = pub[lane >> 2][lane & 3];
      __hip_atomic_store(hdata + (parity << 12) + (blockIdx.x << 6) + lane, v,
                         __ATOMIC_RELAXED, __HIP_MEMORY_SCOPE_AGENT);
      asm volatile("s_waitcnt vmcnt(0)" ::: "memory");   // wave's stores at MALL
      if (lane == 0)
        __hip_atomic_store(flags + (blockIdx.x << 4), (unsigned)(t + 1),
                           __ATOMIC_RELAXED, __HIP_MEMORY_SCOPE_AGENT);
    }

    // every wave: poll all 64 padded flags (1 per lane)
    {
      const unsigned tgt = (unsigned)(t + 1);
      for (;;) {
        unsigned f = __hip_atomic_load(flags + (lane << 4), __ATOMIC_RELAXED,
                                       __HIP_MEMORY_SCOPE_AGENT);
        if (__all(f >= tgt)) break;
      }
    }
    // make remote publishes visible to plain loads (buffer_inv: L1+L2 invalidate)
    __builtin_amdgcn_fence(__ATOMIC_ACQUIRE, "agent");

    // gather: thread tid owns column tid -> one cached float4 load
    float4 hv = *(const float4*)(hdata + (parity << 12) + (tid << 2));
    h_lds[tid]          = hv.x;
    h_lds[HH + tid]     = hv.y;
    h_lds[2 * HH + tid] = hv.z;
    h_lds[3 * HH + tid] = hv.w;
    __syncthreads();                   // barrier2: h_lds complete for next step
  }
}

// ---------------- gate = sigmoid(states @ gate_w^T + gate_b), one wave per row ----------------
__global__ __launch_bounds__(256) void gate_kernel(
    const float* __restrict__ states, const float* __restrict__ gate_w,
    const float* __restrict__ gate_b, float* __restrict__ out)
{
  const int lane = threadIdx.x & 63;
  const int row = (blockIdx.x << 2) + (threadIdx.x >> 6);
  float s = 0.f;
#pragma unroll
  for (int i = 0; i < 16; ++i)
    s += states[(size_t)row * HH + (i << 6) + lane] * gate_w[(i << 6) + lane];
#pragma unroll
  for (int off = 32; off >= 1; off >>= 1) s += __shfl_xor(s, off, 64);
  if (lane == 0) out[row] = sigmoidf_(s + gate_b[0]);
}

// ---------------- build next_keys / next_tokens in d_out ----------------
// NOTE: harness reads the whole d_out as float32, so next_tokens must be
// stored as float32 VALUES (exact for ids < 2^24), not int32 bit patterns.
__global__ __launch_bounds__(256) void copy_next(
    const float* __restrict__ past_keys, const float* __restrict__ ck,
    const int* __restrict__ past_tokens, const int* __restrict__ input_ids,
    float* __restrict__ nk, float* __restrict__ ntokf)
{
  const int i = blockIdx.x * 256 + threadIdx.x;   // float4 index over B*T*64
  if (i < BB * TT * 64) {
    int b = i / (TT * 64);
    int rem = i - b * (TT * 64);
    int t = rem >> 6, c = rem & 63;
    float4 v;
    if (t < MM) v = ((const float4*)past_keys)[((b << 10) + t) * 64 + c];
    else        v = ((const float4*)ck)[((b << 9) + (t - MM)) * 64 + c];
    ((float4*)nk)[i] = v;
  }
  if (i < BB * TT) {
    int b = i / TT, t = i - b * TT;
    int tok = (t < MM) ? past_tokens[(b << 10) + t] : input_ids[(b << 9) + t - MM];
    ntokf[i] = (float)tok;
  }
}

// ---------------- fused streaming attention + token scatter ----------------
__global__ __launch_bounds__(256) void attn_scatter(
    const float* __restrict__ qbuf,   // [B*S][DM]
    const float* __restrict__ nk,     // [B][T][DM] (d_out)
    const float* __restrict__ ntokf,  // [B][T]     (d_out, float-encoded ids)
    const float* __restrict__ gate,   // [B*S]
    const float* __restrict__ msp,    // [1] mem_scale
    float* __restrict__ logits)       // [B*S][V]
{
  __shared__ float q_s[8][260];
  __shared__ float k_s[32][260];
  const int b = blockIdx.y;
  const int s0 = blockIdx.x << 3;
  const int tid = threadIdx.x, lane = tid & 63, wv = tid >> 6;
  const int half = lane >> 5, tl = lane & 31;
  const int ss = wv + (half << 2);        // this thread's s row (0..7)
  const int sg = s0 + ss;
  const int limit = MM + sg;              // valid keys: t < limit (strictly-past causal)

  for (int i = tid; i < 8 * 256; i += 256)
    q_s[i >> 8][i & 255] = qbuf[(size_t)((b << 9) + s0 + (i >> 8)) * DM + (i & 255)];

  const int kr = tid >> 3, kc = (tid & 7) << 5;
  float mx = -1e30f, sum = 0.f;
  float fscale = 0.f;

  for (int pass = 0; pass < 2; ++pass) {
    if (pass == 1) {
      // combine online (mx,sum) across the 32-lane half owning this row
#pragma unroll
      for (int off = 16; off >= 1; off >>= 1) {
        float mo = __shfl_xor(mx, off, 64);
        float so = __shfl_xor(sum, off, 64);
        float m2 = fmaxf(mx, mo);
        sum = sum * __expf(mx - m2) + so * __expf(mo - m2);
        mx = m2;
      }
      fscale = gate[(b << 9) + sg] * msp[0] / sum;
    }
    for (int tile = 0; tile < 48; ++tile) {
      __syncthreads();
      {
        const float4* src = (const float4*)(nk + ((size_t)(b * TT + (tile << 5) + kr) << 8) + kc);
        float4* dst = (float4*)(&k_s[kr][kc]);
#pragma unroll
        for (int u = 0; u < 8; ++u) dst[u] = src[u];
      }
      __syncthreads();
      int t = (tile << 5) + tl;
      if (t < limit) {
        float a = 0.f;
#pragma unroll 8
        for (int d = 0; d < 256; d += 4) {
          float4 kv = *(const float4*)&k_s[tl][d];
          float4 qv = *(const float4*)&q_s[ss][d];
          a += kv.x * qv.x + kv.y * qv.y + kv.z * qv.z + kv.w * qv.w;
        }
        a *= 0.0625f;   // 1/sqrt(256)
        if (pass == 0) {
          float m2 = fmaxf(mx, a);
          sum = sum * __expf(mx - m2) + __expf(a - m2);
          mx = m2;
        } else {
          int tok = (int)ntokf[b * TT + t];
          atomicAdd(logits + (size_t)((b << 9) + sg) * VV + tok,
                    __expf(a - mx) * fscale);
        }
      }
    }
  }
}

// ---------------- host launch ----------------
extern "C" void kernel_launch(void* const* d_in, const int* in_sizes, int n_in,
                              void* d_out, int out_size, void* d_ws, size_t ws_size,
                              hipStream_t stream) {
  (void)in_sizes; (void)n_in; (void)out_size; (void)ws_size;
  const int*   input_ids   = (const int*)  d_in[0];
  const int*   past_tokens = (const int*)  d_in[1];
  const float* past_keys   = (const float*)d_in[2];
  const int*   untied_ids  = (const int*)  d_in[3];
  const float* emb         = (const float*)d_in[4];
  const float* w_ih        = (const float*)d_in[5];
  const float* w_hh        = (const float*)d_in[6];
  const float* b_ih        = (const float*)d_in[7];
  const float* b_hh        = (const float*)d_in[8];
  const float* q_w         = (const float*)d_in[9];
  const float* q_b         = (const float*)d_in[10];
  const float* k_w         = (const float*)d_in[11];
  const float* k_b         = (const float*)d_in[12];
  const float* gate_w      = (const float*)d_in[13];
  const float* gate_b      = (const float*)d_in[14];
  const float* fc_w        = (const float*)d_in[15];
  const float* fc_b        = (const float*)d_in[16];
  const float* proj_w      = (const float*)d_in[17];
  const float* proj_b      = (const float*)d_in[18];
  const float* out_bias    = (const float*)d_in[19];
  const float* part_w      = (const float*)d_in[20];
  const float* part_b      = (const float*)d_in[21];
  const float* mem_scale   = (const float*)d_in[22];

  char* ws = (char*)d_ws;
  unsigned* flags = (unsigned*)ws;                 // 4 KB (64 slots x 64B stride)
  float* hdata    = (float*)(ws + 4096);           // 2*1024*4 f32 = 32 KB
  float* gatebuf  = (float*)(ws + 69632);          // 2048 f32
  float* qb       = (float*)(ws + 81920);          // 2048*256 f32
  float* ckb      = (float*)(ws + 2179072);        // 2048*256 f32
  float* xp       = (float*)(ws + 4276224);        // 2048*3072 f32
  float* states   = (float*)(ws + 29442048);       // 2048*1024 f32
  float* head     = (float*)(ws + 37830656);       // 2048*2048 f32
  float* base     = (float*)(ws + 54607872);       // 2048*512 f32
  // ws high-water: 58,802,176 bytes

  float* logits = (float*)d_out;                   // [2048][32000]
  float* nk     = logits + 65536000ll;             // [4][1536][256]
  float* ntokf  = logits + 67108864ll;             // [4][1536] (float-encoded ids)

  // zero epoch flags (+ hdata region, harmless)
  hipMemsetAsync(ws, 0, 36864, stream);

  // xp = emb[input_ids] @ w_ih^T + b_ih        [2048, 3072]
  gemm_k<128, 8><<<dim3(3072 / 128, 2048 / 128), 256, 0, stream>>>(
      emb, input_ids, w_ih, b_ih, xp, EE, 3072, 0, nullptr);

  // sequential GRU over S=512 steps -> states  [2048, 1024]
  gru_scan<<<64, 1024, 0, stream>>>(xp, w_hh, b_hh, states, hdata, flags);

  // head = square(relu(states @ fc_w^T + fc_b))  [2048, 2048]
  gemm_k<128, 8><<<dim3(2048 / 128, 2048 / 128), 256, 0, stream>>>(
      states, nullptr, fc_w, fc_b, head, HH, 2048, 1, nullptr);

  // base = head @ proj_w^T + proj_b            [2048, 512]
  gemm_k<64, 4><<<dim3(512 / 64, 2048 / 64), 256, 0, stream>>>(
      head, nullptr, proj_w, proj_b, base, 2048, EE, 0, nullptr);

  // logits = base @ emb^T + out_bias           [2048, 32000]
  gemm_k<128, 8><<<dim3(VV / 128, 2048 / 128), 256, 0, stream>>>(
      base, nullptr, emb, out_bias, logits, EE, VV, 0, nullptr);

  // logits[:, untied_ids] += base @ part_w^T + part_b   (atomic scatter epilogue)
  gemm_k<128, 8><<<dim3(UU / 128, 2048 / 128), 256, 0, stream>>>(
      base, nullptr, part_w, part_b, logits, EE, VV, 0, untied_ids);

  // q / ck projections                          [2048, 256]
  gemm_k<64, 4><<<dim3(DM / 64, 2048 / 64), 256, 0, stream>>>(
      states, nullptr, q_w, q_b, qb, HH, DM, 0, nullptr);
  gemm_k<64, 4><<<dim3(DM / 64, 2048 / 64), 256, 0, stream>>>(
      states, nullptr, k_w, k_b, ckb, HH, DM, 0, nullptr);

  // gate scalar per row
  gate_kernel<<<512, 256, 0, stream>>>(states, gate_w, gate_b, gatebuf);

  // next_keys / next_tokens (also the attention's key/token source)
  copy_next<<<1536, 256, 0, stream>>>(past_keys, ckb, past_tokens, input_ids, nk, ntokf);

  // streaming attention + token scatter into logits
  attn_scatter<<<dim3(SS / 8, BB), 256, 0, stream>>>(qb, nk, ntokf, gatebuf, mem_scale, logits);
}

// Round 6
// 7192.062 us; speedup vs baseline: 1.5693x; 1.5693x over previous
//
#include <hip/hip_runtime.h>
#include <cstddef>
#include <cstring>

// Shapes (fixed by the reference)
#define BB 4
#define SS 512
#define VV 32000
#define EE 512
#define HH 1024
#define DM 256
#define UU 4096
#define MM 1024
#define TT 1536   // MM + SS

// ---------------- device helpers ----------------
__device__ __forceinline__ unsigned long long agent_ld64(const unsigned long long* p) {
  return __hip_atomic_load(const_cast<unsigned long long*>(p), __ATOMIC_RELAXED,
                           __HIP_MEMORY_SCOPE_AGENT);
}
__device__ __forceinline__ void agent_st64(unsigned long long* p, unsigned long long v) {
  __hip_atomic_store(p, v, __ATOMIC_RELAXED, __HIP_MEMORY_SCOPE_AGENT);
}
__device__ __forceinline__ float sigmoidf_(float x) { return 1.f / (1.f + __expf(-x)); }

// ---------------- generic fp32 GEMM:  C[M,N] = act( A[M,K] @ W[N,K]^T + bias ) ----------------
// LDS fragments are read as float4 (ds_read_b128): PITCH=136 floats -> 544B rows (16B-aligned),
// micro-tile base tr*8 floats = 32B-aligned. 4 b128 reads per 64 FMAs per thread (was 16 b32).
template <int TILE, int MICRO>
__global__ __launch_bounds__(256) void gemm_k(
    const float* __restrict__ A, const int* __restrict__ a_idx,
    const float* __restrict__ W, const float* __restrict__ bias,
    float* __restrict__ C, int K, int ldc, int act, const int* __restrict__ sidx)
{
  constexpr int PITCH = TILE + 8;           // 136 / 72: rows stay 16B-aligned
  __shared__ float As[16][PITCH];
  __shared__ float Ws[16][PITCH];
  const int tid = threadIdx.x;
  const int bm = blockIdx.y * TILE, bn = blockIdx.x * TILE;
  const int tr = tid >> 4, tc = tid & 15;
  const int lk = tid & 15, lr0 = tid >> 4;
  float acc[MICRO][MICRO] = {};

  for (int k0 = 0; k0 < K; k0 += 16) {
#pragma unroll
    for (int jj = 0; jj < TILE / 16; ++jj) {
      int row = lr0 + (jj << 4);
      int am = bm + row;
      int ar = a_idx ? a_idx[am] : am;
      As[lk][row] = A[(size_t)ar * K + k0 + lk];
      Ws[lk][row] = W[(size_t)(bn + row) * K + k0 + lk];
    }
    __syncthreads();
#pragma unroll
    for (int kk = 0; kk < 16; ++kk) {
      float av[MICRO], wv[MICRO];
#pragma unroll
      for (int i4 = 0; i4 < MICRO / 4; ++i4)
        *(float4*)(av + 4 * i4) = *(const float4*)(&As[kk][tr * MICRO] + 4 * i4);
#pragma unroll
      for (int j4 = 0; j4 < MICRO / 4; ++j4)
        *(float4*)(wv + 4 * j4) = *(const float4*)(&Ws[kk][tc * MICRO] + 4 * j4);
#pragma unroll
      for (int i = 0; i < MICRO; ++i)
#pragma unroll
        for (int j = 0; j < MICRO; ++j) acc[i][j] += av[i] * wv[j];
    }
    __syncthreads();
  }

#pragma unroll
  for (int i = 0; i < MICRO; ++i) {
    int m = bm + tr * MICRO + i;
    float tmp[MICRO];
#pragma unroll
    for (int j = 0; j < MICRO; ++j) {
      int n = bn + tc * MICRO + j;
      float v = acc[i][j] + bias[n];
      if (act == 1) { v = fmaxf(v, 0.f); v *= v; }   // square(relu(x))
      tmp[j] = v;
    }
    if (sidx) {
#pragma unroll
      for (int j = 0; j < MICRO; ++j)
        atomicAdd(C + (size_t)m * ldc + sidx[bn + tc * MICRO + j], tmp[j]);
    } else {
      float* cp = C + (size_t)m * ldc + bn + tc * MICRO;
#pragma unroll
      for (int j4 = 0; j4 < MICRO / 4; ++j4)
        *(float4*)(cp + 4 * j4) =
            make_float4(tmp[4 * j4], tmp[4 * j4 + 1], tmp[4 * j4 + 2], tmp[4 * j4 + 3]);
    }
  }
}

// ---------------- GRU scan: persistent grid, one wave per h-column ----------------
// 64 WGs x 1024 threads = 1024 waves = 1024 columns. Recurrent weights in registers.
// (R1 protocol, best measured: 3987us.) Per step:
//   compute from LDS-staged h -> lane0 publishes h (2x8B agent stores, [j][4] packed)
//   -> __syncthreads (vmcnt drain) -> tid0 release-stores arr[wg*16]=t+1 (64B-padded slot)
//   -> wave0 polls all 64 slots (1 load/lane, s_sleep backoff)
//   -> cooperative 16KB gather of h_t into LDS (2x8B agent loads/thread).
__global__ __launch_bounds__(1024, 1) void gru_scan(
    const float* __restrict__ xp,    // [B*S][3H]  (x@w_ih^T + b_ih)
    const float* __restrict__ w_hh,  // [3H][H]
    const float* __restrict__ b_hh,  // [3H]
    float* __restrict__ states,      // [B*S][H]
    float* hbuf,                     // [2][H][4]  (packed per-column batch quads)
    unsigned* arr)                   // [64*16] per-WG epoch slots (64B stride, zeroed)
{
  __shared__ float h_lds[4 * HH];    // 16 KB: h for all 4 batches, [bb][j]
  const int tid = threadIdx.x;
  const int lane = tid & 63;
  const int wv = tid >> 6;
  const int j = (blockIdx.x << 4) + wv;   // h column

  float wreg[3][16];
#pragma unroll
  for (int g = 0; g < 3; ++g) {
    const float* wr = w_hh + (size_t)((g << 10) + j) * HH + lane;
#pragma unroll
    for (int i = 0; i < 16; ++i) wreg[g][i] = wr[i << 6];
  }
  const float bh0 = b_hh[j], bh1 = b_hh[HH + j], bh2 = b_hh[2 * HH + j];

  // h0 = 0
  for (int i = tid; i < 4 * HH; i += 1024) h_lds[i] = 0.f;
  __syncthreads();

  for (int t = 0; t < SS; ++t) {
    unsigned long long* hdw =
        (unsigned long long*)(hbuf + (((t + 1) & 1) << 12));   // 4096 floats per buffer

    // xp loads first so their latency hides under LDS reads + FMAs
    float xr[4], xz[4], xn[4];
#pragma unroll
    for (int bb = 0; bb < 4; ++bb) {
      const float* xpr = xp + (size_t)((bb << 9) + t) * 3072 + j;
      xr[bb] = xpr[0]; xz[bb] = xpr[HH]; xn[bb] = xpr[2 * HH];
    }

    float acc[4][3] = {};
    float hold[4];
#pragma unroll
    for (int bb = 0; bb < 4; ++bb) {
      hold[bb] = h_lds[(bb << 10) + j];
#pragma unroll
      for (int i = 0; i < 16; ++i) {
        float hv = h_lds[(bb << 10) + (i << 6) + lane];
        acc[bb][0] += hv * wreg[0][i];
        acc[bb][1] += hv * wreg[1][i];
        acc[bb][2] += hv * wreg[2][i];
      }
    }
#pragma unroll
    for (int off = 32; off >= 1; off >>= 1)
#pragma unroll
      for (int bb = 0; bb < 4; ++bb) {
        acc[bb][0] += __shfl_xor(acc[bb][0], off, 64);
        acc[bb][1] += __shfl_xor(acc[bb][1], off, 64);
        acc[bb][2] += __shfl_xor(acc[bb][2], off, 64);
      }
    if (lane == 0) {
      float hv4[4];
#pragma unroll
      for (int bb = 0; bb < 4; ++bb) {
        float r = sigmoidf_(xr[bb] + acc[bb][0] + bh0);
        float z = sigmoidf_(xz[bb] + acc[bb][1] + bh1);
        float n = tanhf(xn[bb] + r * (acc[bb][2] + bh2));
        hv4[bb] = (1.f - z) * n + z * hold[bb];
        states[(size_t)((bb << 9) + t) * HH + j] = hv4[bb];
      }
      unsigned long long w0, w1;
      __builtin_memcpy(&w0, &hv4[0], 8);
      __builtin_memcpy(&w1, &hv4[2], 8);
      agent_st64(hdw + 2 * j, w0);
      agent_st64(hdw + 2 * j + 1, w1);
    }
    if (t == SS - 1) break;            // last state written; no more exchange needed

    __syncthreads();                   // drains each wave's vmcnt -> h stores visible-ordered
    if (tid == 0)
      __hip_atomic_store(arr + (blockIdx.x << 4), (unsigned)(t + 1), __ATOMIC_RELEASE,
                         __HIP_MEMORY_SCOPE_AGENT);
    if (tid < 64) {                    // wave 0 polls all 64 epoch slots (64B-padded)
      const unsigned tgt = (unsigned)(t + 1);
      for (;;) {
        unsigned a = __hip_atomic_load(arr + (lane << 4), __ATOMIC_RELAXED,
                                       __HIP_MEMORY_SCOPE_AGENT);
        if (__all(a >= tgt)) break;
        __builtin_amdgcn_s_sleep(1);
      }
    }
    __syncthreads();

    // cooperative gather: h_t (16 KB) -> LDS, 2 x 8B agent loads per thread (col j = tid)
    const unsigned long long* hsrc =
        (const unsigned long long*)(hbuf + (((t + 1) & 1) << 12));
    unsigned long long v0 = agent_ld64(hsrc + 2 * tid);
    unsigned long long v1 = agent_ld64(hsrc + 2 * tid + 1);
    float f01[2], f23[2];
    __builtin_memcpy(f01, &v0, 8);
    __builtin_memcpy(f23, &v1, 8);
    h_lds[tid]            = f01[0];
    h_lds[HH + tid]       = f01[1];
    h_lds[2 * HH + tid]   = f23[0];
    h_lds[3 * HH + tid]   = f23[1];
    __syncthreads();
  }
}

// ---------------- gate = sigmoid(states @ gate_w^T + gate_b), one wave per row ----------------
__global__ __launch_bounds__(256) void gate_kernel(
    const float* __restrict__ states, const float* __restrict__ gate_w,
    const float* __restrict__ gate_b, float* __restrict__ out)
{
  const int lane = threadIdx.x & 63;
  const int row = (blockIdx.x << 2) + (threadIdx.x >> 6);
  float s = 0.f;
#pragma unroll
  for (int i = 0; i < 16; ++i)
    s += states[(size_t)row * HH + (i << 6) + lane] * gate_w[(i << 6) + lane];
#pragma unroll
  for (int off = 32; off >= 1; off >>= 1) s += __shfl_xor(s, off, 64);
  if (lane == 0) out[row] = sigmoidf_(s + gate_b[0]);
}

// ---------------- build next_keys / next_tokens in d_out ----------------
// NOTE: harness reads the whole d_out as float32, so next_tokens must be
// stored as float32 VALUES (exact for ids < 2^24), not int32 bit patterns.
__global__ __launch_bounds__(256) void copy_next(
    const float* __restrict__ past_keys, const float* __restrict__ ck,
    const int* __restrict__ past_tokens, const int* __restrict__ input_ids,
    float* __restrict__ nk, float* __restrict__ ntokf)
{
  const int i = blockIdx.x * 256 + threadIdx.x;   // float4 index over B*T*64
  if (i < BB * TT * 64) {
    int b = i / (TT * 64);
    int rem = i - b * (TT * 64);
    int t = rem >> 6, c = rem & 63;
    float4 v;
    if (t < MM) v = ((const float4*)past_keys)[((b << 10) + t) * 64 + c];
    else        v = ((const float4*)ck)[((b << 9) + (t - MM)) * 64 + c];
    ((float4*)nk)[i] = v;
  }
  if (i < BB * TT) {
    int b = i / TT, t = i - b * TT;
    int tok = (t < MM) ? past_tokens[(b << 10) + t] : input_ids[(b << 9) + t - MM];
    ntokf[i] = (float)tok;
  }
}

// ---------------- fused streaming attention + token scatter ----------------
__global__ __launch_bounds__(256) void attn_scatter(
    const float* __restrict__ qbuf,   // [B*S][DM]
    const float* __restrict__ nk,     // [B][T][DM] (d_out)
    const float* __restrict__ ntokf,  // [B][T]     (d_out, float-encoded ids)
    const float* __restrict__ gate,   // [B*S]
    const float* __restrict__ msp,    // [1] mem_scale
    float* __restrict__ logits)       // [B*S][V]
{
  __shared__ float q_s[8][260];
  __shared__ float k_s[32][260];
  const int b = blockIdx.y;
  const int s0 = blockIdx.x << 3;
  const int tid = threadIdx.x, lane = tid & 63, wv = tid >> 6;
  const int half = lane >> 5, tl = lane & 31;
  const int ss = wv + (half << 2);        // this thread's s row (0..7)
  const int sg = s0 + ss;
  const int limit = MM + sg;              // valid keys: t < limit (strictly-past causal)

  for (int i = tid; i < 8 * 256; i += 256)
    q_s[i >> 8][i & 255] = qbuf[(size_t)((b << 9) + s0 + (i >> 8)) * DM + (i & 255)];

  const int kr = tid >> 3, kc = (tid & 7) << 5;
  float mx = -1e30f, sum = 0.f;
  float fscale = 0.f;

  for (int pass = 0; pass < 2; ++pass) {
    if (pass == 1) {
      // combine online (mx,sum) across the 32-lane half owning this row
#pragma unroll
      for (int off = 16; off >= 1; off >>= 1) {
        float mo = __shfl_xor(mx, off, 64);
        float so = __shfl_xor(sum, off, 64);
        float m2 = fmaxf(mx, mo);
        sum = sum * __expf(mx - m2) + so * __expf(mo - m2);
        mx = m2;
      }
      fscale = gate[(b << 9) + sg] * msp[0] / sum;
    }
    for (int tile = 0; tile < 48; ++tile) {
      __syncthreads();
      {
        const float4* src = (const float4*)(nk + ((size_t)(b * TT + (tile << 5) + kr) << 8) + kc);
        float4* dst = (float4*)(&k_s[kr][kc]);
#pragma unroll
        for (int u = 0; u < 8; ++u) dst[u] = src[u];
      }
      __syncthreads();
      int t = (tile << 5) + tl;
      if (t < limit) {
        float a = 0.f;
#pragma unroll 8
        for (int d = 0; d < 256; d += 4) {
          float4 kv = *(const float4*)&k_s[tl][d];
          float4 qv = *(const float4*)&q_s[ss][d];
          a += kv.x * qv.x + kv.y * qv.y + kv.z * qv.z + kv.w * qv.w;
        }
        a *= 0.0625f;   // 1/sqrt(256)
        if (pass == 0) {
          float m2 = fmaxf(mx, a);
          sum = sum * __expf(mx - m2) + __expf(a - m2);
          mx = m2;
        } else {
          int tok = (int)ntokf[b * TT + t];
          atomicAdd(logits + (size_t)((b << 9) + sg) * VV + tok,
                    __expf(a - mx) * fscale);
        }
      }
    }
  }
}

// ---------------- host launch ----------------
extern "C" void kernel_launch(void* const* d_in, const int* in_sizes, int n_in,
                              void* d_out, int out_size, void* d_ws, size_t ws_size,
                              hipStream_t stream) {
  (void)in_sizes; (void)n_in; (void)out_size; (void)ws_size;
  const int*   input_ids   = (const int*)  d_in[0];
  const int*   past_tokens = (const int*)  d_in[1];
  const float* past_keys   = (const float*)d_in[2];
  const int*   untied_ids  = (const int*)  d_in[3];
  const float* emb         = (const float*)d_in[4];
  const float* w_ih        = (const float*)d_in[5];
  const float* w_hh        = (const float*)d_in[6];
  const float* b_ih        = (const float*)d_in[7];
  const float* b_hh        = (const float*)d_in[8];
  const float* q_w         = (const float*)d_in[9];
  const float* q_b         = (const float*)d_in[10];
  const float* k_w         = (const float*)d_in[11];
  const float* k_b         = (const float*)d_in[12];
  const float* gate_w      = (const float*)d_in[13];
  const float* gate_b      = (const float*)d_in[14];
  const float* fc_w        = (const float*)d_in[15];
  const float* fc_b        = (const float*)d_in[16];
  const float* proj_w      = (const float*)d_in[17];
  const float* proj_b      = (const float*)d_in[18];
  const float* out_bias    = (const float*)d_in[19];
  const float* part_w      = (const float*)d_in[20];
  const float* part_b      = (const float*)d_in[21];
  const float* mem_scale   = (const float*)d_in[22];

  char* ws = (char*)d_ws;
  unsigned* arr   = (unsigned*)ws;                 // 4 KB (64 slots x 64B stride)
  float* hbuf     = (float*)(ws + 4096);           // 2*1024*4 f32 = 32 KB, [buf][j][bb]
  float* gatebuf  = (float*)(ws + 36864);          // 2048 f32
  float* qb       = (float*)(ws + 65536);          // 2048*256 f32
  float* ckb      = (float*)(ws + 2162688);        // 2048*256 f32
  float* xp       = (float*)(ws + 4259840);        // 2048*3072 f32
  float* states   = (float*)(ws + 29425664);       // 2048*1024 f32
  float* head     = (float*)(ws + 37814272);       // 2048*2048 f32
  float* base     = (float*)(ws + 54591488);       // 2048*512 f32
  // ws high-water: 58,785,792 bytes

  float* logits = (float*)d_out;                   // [2048][32000]
  float* nk     = logits + 65536000ll;             // [4][1536][256]
  float* ntokf  = logits + 67108864ll;             // [4][1536] (float-encoded ids)

  // zero epoch slots (+ h ping-pong region, harmless)
  hipMemsetAsync(ws, 0, 45056, stream);

  // xp = emb[input_ids] @ w_ih^T + b_ih        [2048, 3072]
  gemm_k<128, 8><<<dim3(3072 / 128, 2048 / 128), 256, 0, stream>>>(
      emb, input_ids, w_ih, b_ih, xp, EE, 3072, 0, nullptr);

  // sequential GRU over S=512 steps -> states  [2048, 1024]
  gru_scan<<<64, 1024, 0, stream>>>(xp, w_hh, b_hh, states, hbuf, arr);

  // head = square(relu(states @ fc_w^T + fc_b))  [2048, 2048]
  gemm_k<128, 8><<<dim3(2048 / 128, 2048 / 128), 256, 0, stream>>>(
      states, nullptr, fc_w, fc_b, head, HH, 2048, 1, nullptr);

  // base = head @ proj_w^T + proj_b            [2048, 512]
  gemm_k<64, 4><<<dim3(512 / 64, 2048 / 64), 256, 0, stream>>>(
      head, nullptr, proj_w, proj_b, base, 2048, EE, 0, nullptr);

  // logits = base @ emb^T + out_bias           [2048, 32000]
  gemm_k<128, 8><<<dim3(VV / 128, 2048 / 128), 256, 0, stream>>>(
      base, nullptr, emb, out_bias, logits, EE, VV, 0, nullptr);

  // logits[:, untied_ids] += base @ part_w^T + part_b   (atomic scatter epilogue)
  gemm_k<128, 8><<<dim3(UU / 128, 2048 / 128), 256, 0, stream>>>(
      base, nullptr, part_w, part_b, logits, EE, VV, 0, untied_ids);

  // q / ck projections                          [2048, 256]
  gemm_k<64, 4><<<dim3(DM / 64, 2048 / 64), 256, 0, stream>>>(
      states, nullptr, q_w, q_b, qb, HH, DM, 0, nullptr);
  gemm_k<64, 4><<<dim3(DM / 64, 2048 / 64), 256, 0, stream>>>(
      states, nullptr, k_w, k_b, ckb, HH, DM, 0, nullptr);

  // gate scalar per row
  gate_kernel<<<512, 256, 0, stream>>>(states, gate_w, gate_b, gatebuf);

  // next_keys / next_tokens (also the attention's key/token source)
  copy_next<<<1536, 256, 0, stream>>>(past_keys, ckb, past_tokens, input_ids, nk, ntokf);

  // streaming attention + token scatter into logits
  attn_scatter<<<dim3(SS / 8, BB), 256, 0, stream>>>(qb, nk, ntokf, gatebuf, mem_scale, logits);
}

// Round 7
// 6213.848 us; speedup vs baseline: 1.8164x; 1.1574x over previous
//
#include <hip/hip_runtime.h>
#include <cstddef>
#include <cstring>

// Shapes (fixed by the reference)
#define BB 4
#define SS 512
#define VV 32000
#define EE 512
#define HH 1024
#define DM 256
#define UU 4096
#define MM 1024
#define TT 1536   // MM + SS

// ---------------- device helpers ----------------
__device__ __forceinline__ unsigned long long agent_ld64(const unsigned long long* p) {
  return __hip_atomic_load(const_cast<unsigned long long*>(p), __ATOMIC_RELAXED,
                           __HIP_MEMORY_SCOPE_AGENT);
}
__device__ __forceinline__ void agent_st64(unsigned long long* p, unsigned long long v) {
  __hip_atomic_store(p, v, __ATOMIC_RELAXED, __HIP_MEMORY_SCOPE_AGENT);
}
__device__ __forceinline__ float sigmoidf_(float x) { return 1.f / (1.f + __expf(-x)); }

// ---------------- generic fp32 GEMM:  C[M,N] = act( A[M,K] @ W[N,K]^T + bias ) ----------------
template <int TILE, int MICRO>
__global__ __launch_bounds__(256) void gemm_k(
    const float* __restrict__ A, const int* __restrict__ a_idx,
    const float* __restrict__ W, const float* __restrict__ bias,
    float* __restrict__ C, int K, int ldc, int act, const int* __restrict__ sidx)
{
  constexpr int PITCH = TILE + 4;           // 132 / 68: row bytes stay 16B-aligned
  __shared__ float As[16][PITCH];
  __shared__ float Ws[16][PITCH];
  const int tid = threadIdx.x;
  const int bm = blockIdx.y * TILE, bn = blockIdx.x * TILE;
  const int tr = tid >> 4, tc = tid & 15;
  const int lk = tid & 15, lr0 = tid >> 4;
  float acc[MICRO][MICRO] = {};

  for (int k0 = 0; k0 < K; k0 += 16) {
#pragma unroll
    for (int jj = 0; jj < TILE / 16; ++jj) {
      int row = lr0 + (jj << 4);
      int am = bm + row;
      int ar = a_idx ? a_idx[am] : am;
      As[lk][row] = A[(size_t)ar * K + k0 + lk];
      Ws[lk][row] = W[(size_t)(bn + row) * K + k0 + lk];
    }
    __syncthreads();
#pragma unroll
    for (int kk = 0; kk < 16; ++kk) {
      float av[MICRO], wv[MICRO];
#pragma unroll
      for (int i = 0; i < MICRO; ++i) av[i] = As[kk][tr * MICRO + i];
#pragma unroll
      for (int j = 0; j < MICRO; ++j) wv[j] = Ws[kk][tc * MICRO + j];
#pragma unroll
      for (int i = 0; i < MICRO; ++i)
#pragma unroll
        for (int j = 0; j < MICRO; ++j) acc[i][j] += av[i] * wv[j];
    }
    __syncthreads();
  }

#pragma unroll
  for (int i = 0; i < MICRO; ++i) {
    int m = bm + tr * MICRO + i;
    float tmp[MICRO];
#pragma unroll
    for (int j = 0; j < MICRO; ++j) {
      int n = bn + tc * MICRO + j;
      float v = acc[i][j] + bias[n];
      if (act == 1) { v = fmaxf(v, 0.f); v *= v; }   // square(relu(x))
      tmp[j] = v;
    }
    if (sidx) {
#pragma unroll
      for (int j = 0; j < MICRO; ++j)
        atomicAdd(C + (size_t)m * ldc + sidx[bn + tc * MICRO + j], tmp[j]);
    } else {
      float* cp = C + (size_t)m * ldc + bn + tc * MICRO;
#pragma unroll
      for (int j4 = 0; j4 < MICRO / 4; ++j4)
        *(float4*)(cp + 4 * j4) =
            make_float4(tmp[4 * j4], tmp[4 * j4 + 1], tmp[4 * j4 + 2], tmp[4 * j4 + 3]);
    }
  }
}

// ---------------- GRU scan: 4 INDEPENDENT batch groups ----------------
// Group = one batch: 32 WGs x 512 threads; wave owns 4 adjacent columns (wreg[4][3][16]).
// Tagged-packet exchange (tag<<32|float_bits, 8B single-copy atomic), per-group hbuf.
// Double-buffered LDS h: ONE __syncthreads per step.
//   compute from h_lds[cur] -> lane0 publishes 4 packets (fire-and-forget)
//   -> poll-gather 2 packets/thread into h_lds[nxt] (hides publish ack under same RT)
//   -> barrier -> swap.
// Distance-2 safety: a WG publishes tag t+3 (overwriting its t+1 packets) only after its
// iter-t+1 gather observed ALL tags >= t+2; WG R publishes t+2 only after R's iter-t
// barrier, which is after R's iter-t gather loads (of the t+1 packets) completed.
__global__ __launch_bounds__(512, 1) void gru_scan(
    const float* __restrict__ xp,    // [B*S][3H]  (x@w_ih^T + b_ih)
    const float* __restrict__ w_hh,  // [3H][H]
    const float* __restrict__ b_hh,  // [3H]
    float* __restrict__ states,      // [B*S][H]
    unsigned long long* hbuf)        // [4][2][1024] tagged packets (zeroed, 64 KB)
{
  __shared__ float h_lds[2][HH];     // 8 KB: double-buffered h for THIS batch
  const int tid = threadIdx.x;       // 0..511
  const int lane = tid & 63;
  const int wv = tid >> 6;           // 0..7
  const int bb = blockIdx.x >> 5;    // batch = group
  const int r = blockIdx.x & 31;     // WG within group
  const int c0 = (r << 5) + (wv << 2);   // first of this wave's 4 columns

  unsigned long long* hb = hbuf + ((size_t)bb << 11);   // group base: 2048 packets

  // weights for 4 columns x 3 gates, 16 h-slices per lane
  float wreg[4][3][16];
#pragma unroll
  for (int k = 0; k < 4; ++k)
#pragma unroll
    for (int g = 0; g < 3; ++g) {
      const float* wr = w_hh + (size_t)((g << 10) + c0 + k) * HH + lane;
#pragma unroll
      for (int i = 0; i < 16; ++i) wreg[k][g][i] = wr[i << 6];
    }
  float bh[4][3];
#pragma unroll
  for (int k = 0; k < 4; ++k)
#pragma unroll
    for (int g = 0; g < 3; ++g) bh[k][g] = b_hh[(g << 10) + c0 + k];

  // h0 = 0 in buffer 0
  for (int i = tid; i < HH; i += 512) h_lds[0][i] = 0.f;
  __syncthreads();

  for (int t = 0; t < SS; ++t) {
    const int cur = t & 1, nxt = (t + 1) & 1;
    const float* hc = h_lds[cur];

    // lane0: issue xp + hold loads early (latency hides under dot + butterfly)
    float4 xrv, xzv, xnv, hold;
    if (lane == 0) {
      const float* xpr = xp + (size_t)((bb << 9) + t) * 3072 + c0;
      xrv = *(const float4*)(xpr);
      xzv = *(const float4*)(xpr + HH);
      xnv = *(const float4*)(xpr + 2 * HH);
      hold = *(const float4*)(hc + c0);
    }

    // dot: 16 shared h-reads, 12 FMAs each (4 cols x 3 gates)
    float acc[4][3] = {};
#pragma unroll
    for (int i = 0; i < 16; ++i) {
      float hv = hc[(i << 6) + lane];
#pragma unroll
      for (int k = 0; k < 4; ++k) {
        acc[k][0] += hv * wreg[k][0][i];
        acc[k][1] += hv * wreg[k][1][i];
        acc[k][2] += hv * wreg[k][2][i];
      }
    }
#pragma unroll
    for (int off = 32; off >= 1; off >>= 1)
#pragma unroll
      for (int k = 0; k < 4; ++k) {
        acc[k][0] += __shfl_xor(acc[k][0], off, 64);
        acc[k][1] += __shfl_xor(acc[k][1], off, 64);
        acc[k][2] += __shfl_xor(acc[k][2], off, 64);
      }

    if (lane == 0) {
      const unsigned long long tagw = ((unsigned long long)(unsigned)(t + 1)) << 32;
      float xr[4] = {xrv.x, xrv.y, xrv.z, xrv.w};
      float xz[4] = {xzv.x, xzv.y, xzv.z, xzv.w};
      float xn[4] = {xnv.x, xnv.y, xnv.z, xnv.w};
      float ho[4] = {hold.x, hold.y, hold.z, hold.w};
      float hv4[4];
#pragma unroll
      for (int k = 0; k < 4; ++k) {
        float rr = sigmoidf_(xr[k] + acc[k][0] + bh[k][0]);
        float zz = sigmoidf_(xz[k] + acc[k][1] + bh[k][1]);
        float nn = tanhf(xn[k] + rr * (acc[k][2] + bh[k][2]));
        hv4[k] = (1.f - zz) * nn + zz * ho[k];
      }
      if (t < SS - 1) {
        unsigned long long* dst = hb + ((size_t)nxt << 10) + c0;
#pragma unroll
        for (int k = 0; k < 4; ++k) {
          unsigned hbits;
          __builtin_memcpy(&hbits, &hv4[k], 4);
          agent_st64(dst + k, tagw | (unsigned long long)hbits);  // publish first
        }
      }
      *(float4*)(states + (size_t)((bb << 9) + t) * HH + c0) =
          make_float4(hv4[0], hv4[1], hv4[2], hv4[3]);
    }
    if (t == SS - 1) break;          // last state written; no more exchange needed

    // poll-gather: thread owns packets 2*tid, 2*tid+1 (same 64B line)
    {
      const unsigned tgt = (unsigned)(t + 1);
      const unsigned long long* src = hb + ((size_t)nxt << 10) + (tid << 1);
      unsigned long long p0, p1;
      for (;;) {
        p0 = agent_ld64(src);
        p1 = agent_ld64(src + 1);
        if ((unsigned)(p0 >> 32) >= tgt && (unsigned)(p1 >> 32) >= tgt) break;
      }
      h_lds[nxt][(tid << 1)] = __uint_as_float((unsigned)p0);
      h_lds[nxt][(tid << 1) + 1] = __uint_as_float((unsigned)p1);
    }
    __syncthreads();                 // all waves' gathers into h_lds[nxt] complete
  }
}

// ---------------- gate = sigmoid(states @ gate_w^T + gate_b), one wave per row ----------------
__global__ __launch_bounds__(256) void gate_kernel(
    const float* __restrict__ states, const float* __restrict__ gate_w,
    const float* __restrict__ gate_b, float* __restrict__ out)
{
  const int lane = threadIdx.x & 63;
  const int row = (blockIdx.x << 2) + (threadIdx.x >> 6);
  float s = 0.f;
#pragma unroll
  for (int i = 0; i < 16; ++i)
    s += states[(size_t)row * HH + (i << 6) + lane] * gate_w[(i << 6) + lane];
#pragma unroll
  for (int off = 32; off >= 1; off >>= 1) s += __shfl_xor(s, off, 64);
  if (lane == 0) out[row] = sigmoidf_(s + gate_b[0]);
}

// ---------------- build next_keys / next_tokens in d_out ----------------
// NOTE: harness reads the whole d_out as float32, so next_tokens must be
// stored as float32 VALUES (exact for ids < 2^24), not int32 bit patterns.
__global__ __launch_bounds__(256) void copy_next(
    const float* __restrict__ past_keys, const float* __restrict__ ck,
    const int* __restrict__ past_tokens, const int* __restrict__ input_ids,
    float* __restrict__ nk, float* __restrict__ ntokf)
{
  const int i = blockIdx.x * 256 + threadIdx.x;   // float4 index over B*T*64
  if (i < BB * TT * 64) {
    int b = i / (TT * 64);
    int rem = i - b * (TT * 64);
    int t = rem >> 6, c = rem & 63;
    float4 v;
    if (t < MM) v = ((const float4*)past_keys)[((b << 10) + t) * 64 + c];
    else        v = ((const float4*)ck)[((b << 9) + (t - MM)) * 64 + c];
    ((float4*)nk)[i] = v;
  }
  if (i < BB * TT) {
    int b = i / TT, t = i - b * TT;
    int tok = (t < MM) ? past_tokens[(b << 10) + t] : input_ids[(b << 9) + t - MM];
    ntokf[i] = (float)tok;
  }
}

// ---------------- fused streaming attention + token scatter ----------------
__global__ __launch_bounds__(256) void attn_scatter(
    const float* __restrict__ qbuf,   // [B*S][DM]
    const float* __restrict__ nk,     // [B][T][DM] (d_out)
    const float* __restrict__ ntokf,  // [B][T]     (d_out, float-encoded ids)
    const float* __restrict__ gate,   // [B*S]
    const float* __restrict__ msp,    // [1] mem_scale
    float* __restrict__ logits)       // [B*S][V]
{
  __shared__ float q_s[8][260];
  __shared__ float k_s[32][260];
  const int b = blockIdx.y;
  const int s0 = blockIdx.x << 3;
  const int tid = threadIdx.x, lane = tid & 63, wv = tid >> 6;
  const int half = lane >> 5, tl = lane & 31;
  const int ss = wv + (half << 2);        // this thread's s row (0..7)
  const int sg = s0 + ss;
  const int limit = MM + sg;              // valid keys: t < limit (strictly-past causal)

  for (int i = tid; i < 8 * 256; i += 256)
    q_s[i >> 8][i & 255] = qbuf[(size_t)((b << 9) + s0 + (i >> 8)) * DM + (i & 255)];

  const int kr = tid >> 3, kc = (tid & 7) << 5;
  float mx = -1e30f, sum = 0.f;
  float fscale = 0.f;

  for (int pass = 0; pass < 2; ++pass) {
    if (pass == 1) {
      // combine online (mx,sum) across the 32-lane half owning this row
#pragma unroll
      for (int off = 16; off >= 1; off >>= 1) {
        float mo = __shfl_xor(mx, off, 64);
        float so = __shfl_xor(sum, off, 64);
        float m2 = fmaxf(mx, mo);
        sum = sum * __expf(mx - m2) + so * __expf(mo - m2);
        mx = m2;
      }
      fscale = gate[(b << 9) + sg] * msp[0] / sum;
    }
    for (int tile = 0; tile < 48; ++tile) {
      __syncthreads();
      {
        const float4* src = (const float4*)(nk + ((size_t)(b * TT + (tile << 5) + kr) << 8) + kc);
        float4* dst = (float4*)(&k_s[kr][kc]);
#pragma unroll
        for (int u = 0; u < 8; ++u) dst[u] = src[u];
      }
      __syncthreads();
      int t = (tile << 5) + tl;
      if (t < limit) {
        float a = 0.f;
#pragma unroll 8
        for (int d = 0; d < 256; d += 4) {
          float4 kv = *(const float4*)&k_s[tl][d];
          float4 qv = *(const float4*)&q_s[ss][d];
          a += kv.x * qv.x + kv.y * qv.y + kv.z * qv.z + kv.w * qv.w;
        }
        a *= 0.0625f;   // 1/sqrt(256)
        if (pass == 0) {
          float m2 = fmaxf(mx, a);
          sum = sum * __expf(mx - m2) + __expf(a - m2);
          mx = m2;
        } else {
          int tok = (int)ntokf[b * TT + t];
          atomicAdd(logits + (size_t)((b << 9) + sg) * VV + tok,
                    __expf(a - mx) * fscale);
        }
      }
    }
  }
}

// ---------------- host launch ----------------
extern "C" void kernel_launch(void* const* d_in, const int* in_sizes, int n_in,
                              void* d_out, int out_size, void* d_ws, size_t ws_size,
                              hipStream_t stream) {
  (void)in_sizes; (void)n_in; (void)out_size; (void)ws_size;
  const int*   input_ids   = (const int*)  d_in[0];
  const int*   past_tokens = (const int*)  d_in[1];
  const float* past_keys   = (const float*)d_in[2];
  const int*   untied_ids  = (const int*)  d_in[3];
  const float* emb         = (const float*)d_in[4];
  const float* w_ih        = (const float*)d_in[5];
  const float* w_hh        = (const float*)d_in[6];
  const float* b_ih        = (const float*)d_in[7];
  const float* b_hh        = (const float*)d_in[8];
  const float* q_w         = (const float*)d_in[9];
  const float* q_b         = (const float*)d_in[10];
  const float* k_w         = (const float*)d_in[11];
  const float* k_b         = (const float*)d_in[12];
  const float* gate_w      = (const float*)d_in[13];
  const float* gate_b      = (const float*)d_in[14];
  const float* fc_w        = (const float*)d_in[15];
  const float* fc_b        = (const float*)d_in[16];
  const float* proj_w      = (const float*)d_in[17];
  const float* proj_b      = (const float*)d_in[18];
  const float* out_bias    = (const float*)d_in[19];
  const float* part_w      = (const float*)d_in[20];
  const float* part_b      = (const float*)d_in[21];
  const float* mem_scale   = (const float*)d_in[22];

  char* ws = (char*)d_ws;
  unsigned long long* hbuf = (unsigned long long*)(ws + 4096);  // 4 groups * 2*1024 packets = 64 KB
  float* gatebuf  = (float*)(ws + 69632);          // 2048 f32
  float* qb       = (float*)(ws + 81920);          // 2048*256 f32
  float* ckb      = (float*)(ws + 2179072);        // 2048*256 f32
  float* xp       = (float*)(ws + 4276224);        // 2048*3072 f32
  float* states   = (float*)(ws + 29442048);       // 2048*1024 f32
  float* head     = (float*)(ws + 37830656);       // 2048*2048 f32
  float* base     = (float*)(ws + 54607872);       // 2048*512 f32
  // ws high-water: 58,802,176 bytes

  float* logits = (float*)d_out;                   // [2048][32000]
  float* nk     = logits + 65536000ll;             // [4][1536][256]
  float* ntokf  = logits + 67108864ll;             // [4][1536] (float-encoded ids)

  // zero tagged h packets (tags must start < 1)
  hipMemsetAsync(ws, 0, 69632, stream);

  // xp = emb[input_ids] @ w_ih^T + b_ih        [2048, 3072]
  gemm_k<128, 8><<<dim3(3072 / 128, 2048 / 128), 256, 0, stream>>>(
      emb, input_ids, w_ih, b_ih, xp, EE, 3072, 0, nullptr);

  // sequential GRU over S=512 steps -> states  [2048, 1024]
  // 4 independent batch groups x 32 WGs x 512 threads
  gru_scan<<<128, 512, 0, stream>>>(xp, w_hh, b_hh, states, hbuf);

  // head = square(relu(states @ fc_w^T + fc_b))  [2048, 2048]
  gemm_k<128, 8><<<dim3(2048 / 128, 2048 / 128), 256, 0, stream>>>(
      states, nullptr, fc_w, fc_b, head, HH, 2048, 1, nullptr);

  // base = head @ proj_w^T + proj_b            [2048, 512]
  gemm_k<64, 4><<<dim3(512 / 64, 2048 / 64), 256, 0, stream>>>(
      head, nullptr, proj_w, proj_b, base, 2048, EE, 0, nullptr);

  // logits = base @ emb^T + out_bias           [2048, 32000]
  gemm_k<128, 8><<<dim3(VV / 128, 2048 / 128), 256, 0, stream>>>(
      base, nullptr, emb, out_bias, logits, EE, VV, 0, nullptr);

  // logits[:, untied_ids] += base @ part_w^T + part_b   (atomic scatter epilogue)
  gemm_k<128, 8><<<dim3(UU / 128, 2048 / 128), 256, 0, stream>>>(
      base, nullptr, part_w, part_b, logits, EE, VV, 0, untied_ids);

  // q / ck projections                          [2048, 256]
  gemm_k<64, 4><<<dim3(DM / 64, 2048 / 64), 256, 0, stream>>>(
      states, nullptr, q_w, q_b, qb, HH, DM, 0, nullptr);
  gemm_k<64, 4><<<dim3(DM / 64, 2048 / 64), 256, 0, stream>>>(
      states, nullptr, k_w, k_b, ckb, HH, DM, 0, nullptr);

  // gate scalar per row
  gate_kernel<<<512, 256, 0, stream>>>(states, gate_w, gate_b, gatebuf);

  // next_keys / next_tokens (also the attention's key/token source)
  copy_next<<<1536, 256, 0, stream>>>(past_keys, ckb, past_tokens, input_ids, nk, ntokf);

  // streaming attention + token scatter into logits
  attn_scatter<<<dim3(SS / 8, BB), 256, 0, stream>>>(qb, nk, ntokf, gatebuf, mem_scale, logits);
}